// Round 14
// baseline (73.655 us; speedup 1.0000x reference)
//
#include <hip/hip_runtime.h>

#define BATCH 2
#define NTOK 256
#define DM 512
#define NH 8
#define HDIM 64
#define PD 520      // bf16 row stride for d-major (k=512) pair tensors
#define TSTR 264    // bf16 row stride for j-major (k=256) tensors
#define WSTR 264

typedef unsigned int uint32;
typedef unsigned short ushort16;
typedef __attribute__((ext_vector_type(8))) short bf16x8;
typedef __attribute__((ext_vector_type(4))) float f32x4;

static __device__ __forceinline__ ushort16 bf16_rne(float x) {
  uint32 u = __float_as_uint(x);
  u += 0x7fffu + ((u >> 16) & 1u);
  return (ushort16)(u >> 16);
}
static __device__ __forceinline__ uint32 pack2(float a, float b) {
  return (uint32)bf16_rne(a) | ((uint32)bf16_rne(b) << 16);
}

// 16x32 bf16 MFMA fragment from row-major [16dim][k] bf16: lane l -> row l&15, k-off (l>>4)*8
static __device__ __forceinline__ bf16x8 ldfrag(const ushort16* p0, int stride) {
  int l = threadIdx.x & 63;
  return *(const bf16x8*)(p0 + (size_t)(l & 15) * stride + ((l >> 4) << 3));
}
// same fragment but from fp32 storage, converting inline (identical rounding to prepack)
static __device__ __forceinline__ bf16x8 ldfrag_f32(const float* p0, int stride) {
  int l = threadIdx.x & 63;
  const float* p = p0 + (size_t)(l & 15) * stride + ((l >> 4) << 3);
  float4 a = *(const float4*)p;
  float4 b = *(const float4*)(p + 4);
  bf16x8 r;
  r[0] = (short)bf16_rne(a.x); r[1] = (short)bf16_rne(a.y);
  r[2] = (short)bf16_rne(a.z); r[3] = (short)bf16_rne(a.w);
  r[4] = (short)bf16_rne(b.x); r[5] = (short)bf16_rne(b.y);
  r[6] = (short)bf16_rne(b.z); r[7] = (short)bf16_rne(b.w);
  return r;
}

// ---------------- stage0: prep tables (blocks 0-127) + qkv MFMA (blocks 128-223) ----
// prep: 4 tokens/block, d={2t,2t+1}/thread. qkv: wave = 32i x 64n, K=512, fp32 inputs
// converted inline in the fragment loads (no xb/Wqb staging buffers).
__global__ __launch_bounds__(256) void stage0(
    const float* __restrict__ coords,
    const float* __restrict__ Wb1, const float* __restrict__ bb1,
    const float* __restrict__ Wv1, const float* __restrict__ bv1,
    const float* __restrict__ Wb2,
    const float* __restrict__ X, const float* __restrict__ Wqkv,
    const float* __restrict__ bqkv,
    float* __restrict__ Sv, ushort16* __restrict__ SbW,
    ushort16* __restrict__ Pb, ushort16* __restrict__ PvT,
    ushort16* __restrict__ Pv2T, float* __restrict__ DjT,
    ushort16* __restrict__ Qb, ushort16* __restrict__ Kb,
    ushort16* __restrict__ VTb) {
  __shared__ float redD[4][4][8];
  int t = threadIdx.x;
  int bx = blockIdx.x;

  if (bx >= 128) {
    // ================ qkv path: 96 blocks, 4 waves, wave = 32i x 64n ================
    int bxq = bx - 128;              // 0..95 = 6 n-super x 16 i-tiles
    int nst = bxq / 16, it = bxq & 15;
    int w = t >> 6, lane = t & 63;
    int i0 = it * 32;
    int n0 = nst * 256 + w * 64;
    int col = lane & 15, rb = (lane >> 4) * 4;
    f32x4 acc0[4] = {}, acc1[4] = {};
    const float* a0p = X + (size_t)i0 * DM;
    const float* a1p = X + (size_t)(i0 + 16) * DM;
    const float* bp = Wqkv + (size_t)n0 * DM;
#pragma unroll 2
    for (int kb = 0; kb < 16; ++kb) {
      bf16x8 af0 = ldfrag_f32(a0p + kb * 32, DM);
      bf16x8 af1 = ldfrag_f32(a1p + kb * 32, DM);
#pragma unroll
      for (int nf = 0; nf < 4; ++nf) {
        bf16x8 bf = ldfrag_f32(bp + (size_t)nf * 16 * DM + kb * 32, DM);
        acc0[nf] = __builtin_amdgcn_mfma_f32_16x16x32_bf16(af0, bf, acc0[nf], 0, 0, 0);
        acc1[nf] = __builtin_amdgcn_mfma_f32_16x16x32_bf16(af1, bf, acc1[nf], 0, 0, 0);
      }
    }
#pragma unroll
    for (int half = 0; half < 2; ++half) {
#pragma unroll
      for (int nf = 0; nf < 4; ++nf) {
#pragma unroll
        for (int r = 0; r < 4; ++r) {
          int n = n0 + nf * 16 + col;
          int ig = i0 + half * 16 + rb + r;
          int b = ig >> 8, i = ig & (NTOK - 1);
          float val = (half ? acc1[nf][r] : acc0[nf][r]) + bqkv[n];
          if (n < DM) {
            int h = n >> 6, dp = n & 63;
            Qb[((size_t)(b * NH + h) * NTOK + i) * HDIM + dp] = bf16_rne(val * 0.125f);
          } else if (n < 2 * DM) {
            int u = n - DM; int h = u >> 6, dp = u & 63;
            Kb[((size_t)(b * NH + h) * NTOK + i) * HDIM + dp] = bf16_rne(val);
          } else {
            int u = n - 2 * DM; int h = u >> 6, dp = u & 63;
            VTb[((size_t)(b * NH + h) * HDIM + dp) * TSTR + i] = bf16_rne(val);
          }
        }
      }
    }
    return;
  }

  // ================ prep path: 4 tokens per block, d = {2t, 2t+1} ================
  int b = bx >> 6;
  int t0 = (bx & 63) * 4;
  int lane = t & 63, wv = t >> 6;
  int d0 = t * 2, d1 = t * 2 + 1;
  float w2a[NH], w2b[NH];
#pragma unroll
  for (int h = 0; h < NH; ++h) {
    w2a[h] = Wb2[h * DM + d0];
    w2b[h] = Wb2[h * DM + d1];
  }
  float b1ax = Wb1[d0 * 3 + 0], b1ay = Wb1[d0 * 3 + 1], b1az = Wb1[d0 * 3 + 2];
  float b1bx = Wb1[d1 * 3 + 0], b1by = Wb1[d1 * 3 + 1], b1bz = Wb1[d1 * 3 + 2];
  float v1ax = Wv1[d0 * 3 + 0], v1ay = Wv1[d0 * 3 + 1], v1az = Wv1[d0 * 3 + 2];
  float v1bx = Wv1[d1 * 3 + 0], v1by = Wv1[d1 * 3 + 1], v1bz = Wv1[d1 * 3 + 2];
  float bba = bb1[d0], bbb = bb1[d1];
  float bva = bv1[d0], bvb = bv1[d1];
  ushort16 pvp[2][4], pv2p[2][4];
#pragma unroll
  for (int tt = 0; tt < 4; ++tt) {
    int tok = t0 + tt, q = b * NTOK + tok;
    const float* cp = coords + q * 3;          // uniform -> s_load
    float c0 = cp[0], c1 = cp[1], c2 = cp[2];
    float pba = b1ax * c0 + b1ay * c1 + b1az * c2;
    float pbb = b1bx * c0 + b1by * c1 + b1bz * c2;
    float pva = v1ax * c0 + v1ay * c1 + v1az * c2;
    float pvb = v1bx * c0 + v1by * c1 + v1bz * c2;
    float sba = pba + bba, sbb = pbb + bbb;
    *(float2*)&Sv[(size_t)q * DM + d0] = make_float2(pva + bva, pvb + bvb);
    *(uint32*)&Pb[(size_t)q * PD + d0] = pack2(pba, pbb);
    pvp[0][tt] = bf16_rne(pva);
    pvp[1][tt] = bf16_rne(pvb);
    pv2p[0][tt] = bf16_rne(pva * pva);
    pv2p[1][tt] = bf16_rne(pvb * pvb);
#pragma unroll
    for (int h = 0; h < NH; ++h) {
      size_t base = ((size_t)(b * NH + h) * NTOK + tok) * PD;
      *(uint32*)&SbW[base + d0] = pack2(-0.5f * w2a[h] * sba, -0.5f * w2b[h] * sbb);
    }
    float ua = -0.5f * pba + 0.25f * pba * pba;
    float ub = -0.5f * pbb + 0.25f * pbb * pbb;
    float dp[NH];
#pragma unroll
    for (int h = 0; h < NH; ++h) dp[h] = fmaf(w2a[h], ua, w2b[h] * ub);
#pragma unroll
    for (int off = 32; off >= 1; off >>= 1) {
#pragma unroll
      for (int h = 0; h < NH; ++h) dp[h] += __shfl_xor(dp[h], off);
    }
    if (lane == 0) {
#pragma unroll
      for (int h = 0; h < NH; ++h) redD[wv][tt][h] = dp[h];
    }
  }
  __syncthreads();
  if (t < 32) {
    int tq = t >> 3, hh = t & 7;
    float s = (redD[0][tq][hh] + redD[1][tq][hh]) + (redD[2][tq][hh] + redD[3][tq][hh]);
    DjT[(size_t)(b * NH + hh) * NTOK + t0 + tq] = s;
  }
  uint2 k1, k2;
#pragma unroll
  for (int hh = 0; hh < 2; ++hh) {
    int d = t * 2 + hh;
    k1.x = (uint32)pvp[hh][0] | ((uint32)pvp[hh][1] << 16);
    k1.y = (uint32)pvp[hh][2] | ((uint32)pvp[hh][3] << 16);
    k2.x = (uint32)pv2p[hh][0] | ((uint32)pv2p[hh][1] << 16);
    k2.y = (uint32)pv2p[hh][2] | ((uint32)pv2p[hh][3] << 16);
    *(uint2*)&PvT [((size_t)(b * DM) + d) * TSTR + t0] = k1;
    *(uint2*)&Pv2T[((size_t)(b * DM) + d) * TSTR + t0] = k2;
  }
}

// ---------------- attn_fused2: scores + softmax (LDS) + P1/P2 + Taylor g + out ------
// grid (16 i-tiles, 16 bh), 512 thr = 8 waves.
// score: wave w = 16i x 32j strip; phase A: wave w = 64-d strip;
// phase B: waves 0-3 g@Wv2^T (fp32 Wv2, inline cvt), waves 4-7 Wsm@V; LDS combine.
__global__ __launch_bounds__(512) void attn_fused2(
    const ushort16* __restrict__ Qb, const ushort16* __restrict__ Kb,
    const ushort16* __restrict__ SbW, const ushort16* __restrict__ Pb,
    const float* __restrict__ DjT,
    const ushort16* __restrict__ PvT, const ushort16* __restrict__ Pv2T,
    const float* __restrict__ Sv,
    const float* __restrict__ Wv2, const ushort16* __restrict__ VTb,
    const float* __restrict__ bv2, float* __restrict__ out) {
  __shared__ ushort16 wsh[16][WSTR];     // softmax weights bf16 (8.4 KB)
  __shared__ ushort16 gsh[16][DM + 8];   // g bf16 (16.6 KB)
  __shared__ float fB[16][68];           // 4.3 KB
  __shared__ float redm[8][16];
  __shared__ float reds[8][16];
  int t = threadIdx.x;
  int w = t >> 6, lane = t & 63;
  int bh = blockIdx.y;
  int b = bh >> 3, h = bh & 7;
  int ib = blockIdx.x * 16;
  int col = lane & 15, rb = (lane >> 4) * 4;

  // ======== score: wave w covers j0 = w*32 ========
  {
    int j0 = w * 32;
    f32x4 acc[2] = {};
    {  // qk over K=64
      const ushort16* qbase = Qb + ((size_t)bh * NTOK + ib) * HDIM;
      const ushort16* kbase = Kb + ((size_t)bh * NTOK + j0) * HDIM;
#pragma unroll
      for (int kb = 0; kb < 2; ++kb) {
        bf16x8 af = ldfrag(qbase + kb * 32, HDIM);
#pragma unroll
        for (int jf = 0; jf < 2; ++jf) {
          bf16x8 bf = ldfrag(kbase + (size_t)jf * 16 * HDIM + kb * 32, HDIM);
          acc[jf] = __builtin_amdgcn_mfma_f32_16x16x32_bf16(af, bf, acc[jf], 0, 0, 0);
        }
      }
    }
    {  // C-term over K=512 (-0.5 folded into SbW)
      const ushort16* abase = SbW + ((size_t)bh * NTOK + ib) * PD;
      const ushort16* bbase = Pb + ((size_t)(b * NTOK) + j0) * PD;
#pragma unroll 4
      for (int kb = 0; kb < 16; ++kb) {
        bf16x8 af = ldfrag(abase + kb * 32, PD);
#pragma unroll
        for (int jf = 0; jf < 2; ++jf) {
          bf16x8 bf = ldfrag(bbase + (size_t)jf * 16 * PD + kb * 32, PD);
          acc[jf] = __builtin_amdgcn_mfma_f32_16x16x32_bf16(af, bf, acc[jf], 0, 0, 0);
        }
      }
    }
    float sc[2][4];
#pragma unroll
    for (int jf = 0; jf < 2; ++jf) {
      float dj = DjT[(size_t)bh * NTOK + j0 + jf * 16 + col];
#pragma unroll
      for (int r = 0; r < 4; ++r) sc[jf][r] = acc[jf][r] + dj;
    }
#pragma unroll
    for (int r = 0; r < 4; ++r) {
      float m = fmaxf(sc[0][r], sc[1][r]);
      m = fmaxf(m, __shfl_xor(m, 1));
      m = fmaxf(m, __shfl_xor(m, 2));
      m = fmaxf(m, __shfl_xor(m, 4));
      m = fmaxf(m, __shfl_xor(m, 8));
      if (col == 0) redm[w][rb + r] = m;
    }
    __syncthreads();
    float mrow[4];
#pragma unroll
    for (int r = 0; r < 4; ++r) {
      float m = redm[0][rb + r];
#pragma unroll
      for (int ww = 1; ww < 8; ++ww) m = fmaxf(m, redm[ww][rb + r]);
      mrow[r] = m;
    }
#pragma unroll
    for (int r = 0; r < 4; ++r) {
      float su = 0.f;
#pragma unroll
      for (int jf = 0; jf < 2; ++jf) {
        float e = __expf(sc[jf][r] - mrow[r]);
        sc[jf][r] = e;
        su += e;
      }
      su += __shfl_xor(su, 1);
      su += __shfl_xor(su, 2);
      su += __shfl_xor(su, 4);
      su += __shfl_xor(su, 8);
      if (col == 0) reds[w][rb + r] = su;
    }
    __syncthreads();
#pragma unroll
    for (int r = 0; r < 4; ++r) {
      float stot = 0.f;
#pragma unroll
      for (int ww = 0; ww < 8; ++ww) stot += reds[ww][rb + r];
      float inv = __builtin_amdgcn_rcpf(stot);
#pragma unroll
      for (int jf = 0; jf < 2; ++jf)
        wsh[rb + r][j0 + jf * 16 + col] = bf16_rne(sc[jf][r] * inv);
    }
  }
  __syncthreads();

  // ======== phase A: P1/P2 for d0 = w*64, K=256, A (Wsm) from LDS ========
  {
    int d0 = w * 64;
    f32x4 a1[4] = {}, a2[4] = {};
    const ushort16* b1 = PvT + ((size_t)(b * DM) + d0) * TSTR;
    const ushort16* b2 = Pv2T + ((size_t)(b * DM) + d0) * TSTR;
#pragma unroll 2
    for (int kb = 0; kb < 8; ++kb) {
      bf16x8 af = *(const bf16x8*)&wsh[col][kb * 32 + ((lane >> 4) << 3)];
#pragma unroll
      for (int df = 0; df < 4; ++df) {
        bf16x8 f1 = ldfrag(b1 + (size_t)df * 16 * TSTR + kb * 32, TSTR);
        a1[df] = __builtin_amdgcn_mfma_f32_16x16x32_bf16(af, f1, a1[df], 0, 0, 0);
        bf16x8 f2 = ldfrag(b2 + (size_t)df * 16 * TSTR + kb * 32, TSTR);
        a2[df] = __builtin_amdgcn_mfma_f32_16x16x32_bf16(af, f2, a2[df], 0, 0, 0);
      }
    }
#pragma unroll
    for (int df = 0; df < 4; ++df) {
#pragma unroll
      for (int r = 0; r < 4; ++r) {
        int ig = ib + rb + r;
        int dg = d0 + df * 16 + col;
        float sv = Sv[((size_t)(b * NTOK) + ig) * DM + dg];
        float p1 = a1[df][r], p2 = a2[df][r];
        float g = 0.5f * (sv - p1) + 0.25f * (sv * sv - 2.f * sv * p1 + p2);
        gsh[rb + r][dg] = bf16_rne(g);
      }
    }
  }
  __syncthreads();

  // ======== phase B: split K-work across wave halves ========
  f32x4 acc2 = {};
  if (w < 4) {  // g @ Wv2_h^T, K=512, A from LDS, B fp32 inline-converted
    const float* wvf = Wv2 + (size_t)(h * HDIM + w * 16) * DM;
#pragma unroll 4
    for (int kb = 0; kb < 16; ++kb) {
      bf16x8 af = *(const bf16x8*)&gsh[col][kb * 32 + ((lane >> 4) << 3)];
      bf16x8 bf = ldfrag_f32(wvf + kb * 32, DM);
      acc2 = __builtin_amdgcn_mfma_f32_16x16x32_bf16(af, bf, acc2, 0, 0, 0);
    }
  } else {      // Wsm @ V, K=256, A from LDS
    const ushort16* vtb = VTb + (size_t)(bh * HDIM + (w - 4) * 16) * TSTR;
#pragma unroll 2
    for (int kb = 0; kb < 8; ++kb) {
      bf16x8 af = *(const bf16x8*)&wsh[col][kb * 32 + ((lane >> 4) << 3)];
      bf16x8 bf = ldfrag(vtb + kb * 32, TSTR);
      acc2 = __builtin_amdgcn_mfma_f32_16x16x32_bf16(af, bf, acc2, 0, 0, 0);
    }
  }
  if (w < 4) {
#pragma unroll
    for (int r = 0; r < 4; ++r) fB[rb + r][w * 16 + col] = acc2[r];
  }
  __syncthreads();
  if (w >= 4) {
    int o = h * HDIM + (w - 4) * 16 + col;
    float bv = bv2[o];
#pragma unroll
    for (int r = 0; r < 4; ++r) {
      int ig = ib + rb + r;
      out[((size_t)(b * NTOK) + ig) * DM + o] = fB[rb + r][(w - 4) * 16 + col] + acc2[r] + bv;
    }
  }
}

extern "C" void kernel_launch(void* const* d_in, const int* in_sizes, int n_in,
                              void* d_out, int out_size, void* d_ws, size_t ws_size,
                              hipStream_t stream) {
  const float* x      = (const float*)d_in[0];
  const float* coords = (const float*)d_in[1];
  const float* Wqkv   = (const float*)d_in[2];
  const float* bqkv   = (const float*)d_in[3];
  const float* Wb1    = (const float*)d_in[4];
  const float* bb1    = (const float*)d_in[5];
  const float* Wb2    = (const float*)d_in[6];
  // d_in[7] = bb2: softmax-invariant, unused
  const float* Wv1    = (const float*)d_in[8];
  const float* bv1    = (const float*)d_in[9];
  const float* Wv2    = (const float*)d_in[10];
  const float* bv2    = (const float*)d_in[11];
  float* outp = (float*)d_out;
  float* ws = (float*)d_ws;

  const size_t SZ = (size_t)BATCH * NTOK * DM;           // 262144
  float* Svw = ws;
  float* DjT = ws + SZ;                                  // [bh][j], 4096 floats
  ushort16* SbW  = (ushort16*)(DjT + 4096);              // [bh][tok][PD]
  ushort16* Pbw  = SbW + (size_t)BATCH * NH * NTOK * PD;
  ushort16* PvT  = Pbw + (size_t)BATCH * NTOK * PD;      // [b][d][TSTR]
  ushort16* Pv2T = PvT + (size_t)BATCH * DM * TSTR;
  ushort16* Qb   = Pv2T + (size_t)BATCH * DM * TSTR;     // [bh][i][64]
  ushort16* Kb   = Qb + (size_t)BATCH * NH * NTOK * HDIM;
  ushort16* VTb  = Kb + (size_t)BATCH * NH * NTOK * HDIM;    // [bh][dp][TSTR]

  hipLaunchKernelGGL(stage0, dim3(224), dim3(256), 0, stream,
                     coords, Wb1, bb1, Wv1, bv1, Wb2, x, Wqkv, bqkv,
                     Svw, SbW, Pbw, PvT, Pv2T, DjT, Qb, Kb, VTb);
  hipLaunchKernelGGL(attn_fused2, dim3(16, BATCH * NH), dim3(512), 0, stream,
                     Qb, Kb, SbW, Pbw, DjT, PvT, Pv2T, Svw, Wv2, VTb, bv2, outp);
}

// Round 16
// 54.701 us; speedup vs baseline: 1.3465x; 1.3465x over previous
//
#include <hip/hip_runtime.h>

#define BATCH 2
#define NTOK 256
#define DM 512
#define NH 8
#define HDIM 64
#define PD 520      // bf16 row stride for d-major (k=512) pair tensors
#define TSTR 264    // bf16 row stride for j-major (k=256) tensors
#define WSTR 264

typedef unsigned int uint32;
typedef unsigned short ushort16;
typedef __attribute__((ext_vector_type(8))) short bf16x8;
typedef __attribute__((ext_vector_type(4))) float f32x4;

static __device__ __forceinline__ ushort16 bf16_rne(float x) {
  uint32 u = __float_as_uint(x);
  u += 0x7fffu + ((u >> 16) & 1u);
  return (ushort16)(u >> 16);
}
static __device__ __forceinline__ uint32 pack2(float a, float b) {
  return (uint32)bf16_rne(a) | ((uint32)bf16_rne(b) << 16);
}

// 16x32 bf16 MFMA fragment from row-major [16dim][k]: lane l -> row l&15, k-off (l>>4)*8
static __device__ __forceinline__ bf16x8 ldfrag(const ushort16* p0, int stride) {
  int l = threadIdx.x & 63;
  return *(const bf16x8*)(p0 + (size_t)(l & 15) * stride + ((l >> 4) << 3));
}

// ---------------- stage0: prep tables (blocks 0-127) + bf16 conversion (128-767) ----
__global__ __launch_bounds__(256) void stage0(
    const float* __restrict__ coords,
    const float* __restrict__ Wb1, const float* __restrict__ bb1,
    const float* __restrict__ Wv1, const float* __restrict__ bv1,
    const float* __restrict__ Wb2,
    const float* __restrict__ X, const float* __restrict__ Wqkv,
    const float* __restrict__ Wv2,
    float* __restrict__ Sv, ushort16* __restrict__ SbW,
    ushort16* __restrict__ Pb, ushort16* __restrict__ PvT,
    ushort16* __restrict__ Pv2T, float* __restrict__ DjT,
    ushort16* __restrict__ xb, ushort16* __restrict__ Wqb,
    ushort16* __restrict__ Wv2b) {
  int t = threadIdx.x;
  int bx = blockIdx.x;
  if (bx >= 128) {
    // ---- flat fp32 -> bf16 conversion ----
    const float* src; ushort16* dst; int cb;
    if (bx < 256)      { src = X;    dst = xb;   cb = bx - 128; }
    else if (bx < 640) { src = Wqkv; dst = Wqb;  cb = bx - 256; }
    else               { src = Wv2;  dst = Wv2b; cb = bx - 640; }
    size_t off = ((size_t)cb * 256 + t) * 8;
    float4 f1 = *(const float4*)(src + off);
    float4 f2 = *(const float4*)(src + off + 4);
    uint4 pk;
    pk.x = pack2(f1.x, f1.y); pk.y = pack2(f1.z, f1.w);
    pk.z = pack2(f2.x, f2.y); pk.w = pack2(f2.z, f2.w);
    *(uint4*)&dst[off] = pk;
    return;
  }
  // ---- prep path: 4 tokens per block, d = {2t, 2t+1} per thread ----
  __shared__ float redD[4][8];
  int b = bx >> 6;
  int t0 = (bx & 63) * 4;
  int lane = t & 63, wv = t >> 6;
  int d0 = t * 2, d1 = t * 2 + 1;
  float w2a[NH], w2b[NH];
#pragma unroll
  for (int h = 0; h < NH; ++h) {
    w2a[h] = Wb2[h * DM + d0];
    w2b[h] = Wb2[h * DM + d1];
  }
  float b1ax = Wb1[d0 * 3 + 0], b1ay = Wb1[d0 * 3 + 1], b1az = Wb1[d0 * 3 + 2];
  float b1bx = Wb1[d1 * 3 + 0], b1by = Wb1[d1 * 3 + 1], b1bz = Wb1[d1 * 3 + 2];
  float v1ax = Wv1[d0 * 3 + 0], v1ay = Wv1[d0 * 3 + 1], v1az = Wv1[d0 * 3 + 2];
  float v1bx = Wv1[d1 * 3 + 0], v1by = Wv1[d1 * 3 + 1], v1bz = Wv1[d1 * 3 + 2];
  float bba = bb1[d0], bbb = bb1[d1];
  float bva = bv1[d0], bvb = bv1[d1];
  ushort16 pvp[2][4], pv2p[2][4];
#pragma unroll
  for (int tt = 0; tt < 4; ++tt) {
    int tok = t0 + tt, q = b * NTOK + tok;
    const float* cp = coords + q * 3;          // uniform -> s_load
    float c0 = cp[0], c1 = cp[1], c2 = cp[2];
    float pba = b1ax * c0 + b1ay * c1 + b1az * c2;
    float pbb = b1bx * c0 + b1by * c1 + b1bz * c2;
    float pva = v1ax * c0 + v1ay * c1 + v1az * c2;
    float pvb = v1bx * c0 + v1by * c1 + v1bz * c2;
    float sba = pba + bba, sbb = pbb + bbb;
    *(float2*)&Sv[(size_t)q * DM + d0] = make_float2(pva + bva, pvb + bvb);
    *(uint32*)&Pb[(size_t)q * PD + d0] = pack2(pba, pbb);
    pvp[0][tt] = bf16_rne(pva);
    pvp[1][tt] = bf16_rne(pvb);
    pv2p[0][tt] = bf16_rne(pva * pva);
    pv2p[1][tt] = bf16_rne(pvb * pvb);
#pragma unroll
    for (int h = 0; h < NH; ++h) {
      size_t base = ((size_t)(b * NH + h) * NTOK + tok) * PD;
      *(uint32*)&SbW[base + d0] = pack2(-0.5f * w2a[h] * sba, -0.5f * w2b[h] * sbb);
    }
    float ua = -0.5f * pba + 0.25f * pba * pba;
    float ub = -0.5f * pbb + 0.25f * pbb * pbb;
    float dp[NH];
#pragma unroll
    for (int h = 0; h < NH; ++h) dp[h] = fmaf(w2a[h], ua, w2b[h] * ub);
#pragma unroll
    for (int off = 32; off >= 1; off >>= 1) {
#pragma unroll
      for (int h = 0; h < NH; ++h) dp[h] += __shfl_xor(dp[h], off);
    }
    if (lane == 0) {
#pragma unroll
      for (int h = 0; h < NH; ++h) redD[wv][h] = dp[h];
    }
    __syncthreads();
    if (t < NH)
      DjT[(size_t)(b * NH + t) * NTOK + tok] =
          (redD[0][t] + redD[1][t]) + (redD[2][t] + redD[3][t]);
    __syncthreads();
  }
  uint2 k1, k2;
#pragma unroll
  for (int hh = 0; hh < 2; ++hh) {
    int d = t * 2 + hh;
    k1.x = (uint32)pvp[hh][0] | ((uint32)pvp[hh][1] << 16);
    k1.y = (uint32)pvp[hh][2] | ((uint32)pvp[hh][3] << 16);
    k2.x = (uint32)pv2p[hh][0] | ((uint32)pv2p[hh][1] << 16);
    k2.y = (uint32)pv2p[hh][2] | ((uint32)pv2p[hh][3] << 16);
    *(uint2*)&PvT [((size_t)(b * DM) + d) * TSTR + t0] = k1;
    *(uint2*)&Pv2T[((size_t)(b * DM) + d) * TSTR + t0] = k2;
  }
}

// ---------------- qkv_mfma: qkv = x @ Wqkv^T + bqkv (bf16 MFMA, no LDS) ----------
// grid (12 n-tiles of 128, 32 i-tiles), 128 thr = 2 waves; wave = 16i x 64n, K=512.
__global__ __launch_bounds__(128) void qkv_mfma(
    const ushort16* __restrict__ xb, const ushort16* __restrict__ Wqb,
    const float* __restrict__ bqkv,
    ushort16* __restrict__ Qb, ushort16* __restrict__ Kb,
    ushort16* __restrict__ VTb) {
  int t = threadIdx.x;
  int w = t >> 6, lane = t & 63;
  int n0 = blockIdx.x * 128 + w * 64;   // 64-aligned -> single section+head per wave
  int ibase = blockIdx.y * 16;
  f32x4 acc[4] = {};
  const ushort16* abase = xb + (size_t)ibase * DM;
  const ushort16* bbase = Wqb + (size_t)n0 * DM;
#pragma unroll 4
  for (int kb = 0; kb < 16; ++kb) {
    bf16x8 af = ldfrag(abase + kb * 32, DM);
#pragma unroll
    for (int nf = 0; nf < 4; ++nf) {
      bf16x8 bf = ldfrag(bbase + (size_t)nf * 16 * DM + kb * 32, DM);
      acc[nf] = __builtin_amdgcn_mfma_f32_16x16x32_bf16(af, bf, acc[nf], 0, 0, 0);
    }
  }
  int col = lane & 15, rb = (lane >> 4) * 4;
#pragma unroll
  for (int nf = 0; nf < 4; ++nf) {
#pragma unroll
    for (int r = 0; r < 4; ++r) {
      int n = n0 + nf * 16 + col;
      int ig = ibase + rb + r;
      int b = ig >> 8, i = ig & (NTOK - 1);
      float val = acc[nf][r] + bqkv[n];
      if (n < DM) {
        int h = n >> 6, dp = (nf * 16 + col) & 63;
        Qb[((size_t)(b * NH + h) * NTOK + i) * HDIM + dp] = bf16_rne(val * 0.125f);
      } else if (n < 2 * DM) {
        int u = n - DM; int h = u >> 6, dp = u & 63;
        Kb[((size_t)(b * NH + h) * NTOK + i) * HDIM + dp] = bf16_rne(val);
      } else {
        int u = n - 2 * DM; int h = u >> 6, dp = u & 63;
        VTb[((size_t)(b * NH + h) * HDIM + dp) * TSTR + i] = bf16_rne(val);
      }
    }
  }
}

// ---------------- attn_fused2: scores + softmax (LDS) + P1/P2 + Taylor g + out ------
// grid (16 i-tiles, 16 bh), 512 thr = 8 waves.
// score: wave w = 16i x 32j strip; phase A: wave w = 64-d strip;
// phase B: waves 0-3 g@Wv2^T, waves 4-7 Wsm@V, combine via LDS.
__global__ __launch_bounds__(512) void attn_fused2(
    const ushort16* __restrict__ Qb, const ushort16* __restrict__ Kb,
    const ushort16* __restrict__ SbW, const ushort16* __restrict__ Pb,
    const float* __restrict__ DjT,
    const ushort16* __restrict__ PvT, const ushort16* __restrict__ Pv2T,
    const float* __restrict__ Sv,
    const ushort16* __restrict__ Wv2b, const ushort16* __restrict__ VTb,
    const float* __restrict__ bv2, float* __restrict__ out) {
  __shared__ ushort16 wsh[16][WSTR];     // softmax weights bf16 (8.4 KB)
  __shared__ ushort16 gsh[16][DM + 8];   // g bf16 (16.6 KB)
  __shared__ float fB[16][68];           // 4.3 KB
  __shared__ float redm[8][16];
  __shared__ float reds[8][16];
  int t = threadIdx.x;
  int w = t >> 6, lane = t & 63;
  int bh = blockIdx.y;
  int b = bh >> 3, h = bh & 7;
  int ib = blockIdx.x * 16;
  int col = lane & 15, rb = (lane >> 4) * 4;

  // ======== score: wave w covers j0 = w*32 ========
  {
    int j0 = w * 32;
    f32x4 acc[2] = {};
    {  // qk over K=64
      const ushort16* qbase = Qb + ((size_t)bh * NTOK + ib) * HDIM;
      const ushort16* kbase = Kb + ((size_t)bh * NTOK + j0) * HDIM;
#pragma unroll
      for (int kb = 0; kb < 2; ++kb) {
        bf16x8 af = ldfrag(qbase + kb * 32, HDIM);
#pragma unroll
        for (int jf = 0; jf < 2; ++jf) {
          bf16x8 bf = ldfrag(kbase + (size_t)jf * 16 * HDIM + kb * 32, HDIM);
          acc[jf] = __builtin_amdgcn_mfma_f32_16x16x32_bf16(af, bf, acc[jf], 0, 0, 0);
        }
      }
    }
    {  // C-term over K=512 (-0.5 folded into SbW)
      const ushort16* abase = SbW + ((size_t)bh * NTOK + ib) * PD;
      const ushort16* bbase = Pb + ((size_t)(b * NTOK) + j0) * PD;
#pragma unroll 4
      for (int kb = 0; kb < 16; ++kb) {
        bf16x8 af = ldfrag(abase + kb * 32, PD);
#pragma unroll
        for (int jf = 0; jf < 2; ++jf) {
          bf16x8 bf = ldfrag(bbase + (size_t)jf * 16 * PD + kb * 32, PD);
          acc[jf] = __builtin_amdgcn_mfma_f32_16x16x32_bf16(af, bf, acc[jf], 0, 0, 0);
        }
      }
    }
    float sc[2][4];
#pragma unroll
    for (int jf = 0; jf < 2; ++jf) {
      float dj = DjT[(size_t)bh * NTOK + j0 + jf * 16 + col];
#pragma unroll
      for (int r = 0; r < 4; ++r) sc[jf][r] = acc[jf][r] + dj;
    }
#pragma unroll
    for (int r = 0; r < 4; ++r) {
      float m = fmaxf(sc[0][r], sc[1][r]);
      m = fmaxf(m, __shfl_xor(m, 1));
      m = fmaxf(m, __shfl_xor(m, 2));
      m = fmaxf(m, __shfl_xor(m, 4));
      m = fmaxf(m, __shfl_xor(m, 8));
      if (col == 0) redm[w][rb + r] = m;
    }
    __syncthreads();
    float mrow[4];
#pragma unroll
    for (int r = 0; r < 4; ++r) {
      float m = redm[0][rb + r];
#pragma unroll
      for (int ww = 1; ww < 8; ++ww) m = fmaxf(m, redm[ww][rb + r]);
      mrow[r] = m;
    }
#pragma unroll
    for (int r = 0; r < 4; ++r) {
      float su = 0.f;
#pragma unroll
      for (int jf = 0; jf < 2; ++jf) {
        float e = __expf(sc[jf][r] - mrow[r]);
        sc[jf][r] = e;
        su += e;
      }
      su += __shfl_xor(su, 1);
      su += __shfl_xor(su, 2);
      su += __shfl_xor(su, 4);
      su += __shfl_xor(su, 8);
      if (col == 0) reds[w][rb + r] = su;
    }
    __syncthreads();
#pragma unroll
    for (int r = 0; r < 4; ++r) {
      float stot = 0.f;
#pragma unroll
      for (int ww = 0; ww < 8; ++ww) stot += reds[ww][rb + r];
      float inv = __builtin_amdgcn_rcpf(stot);
#pragma unroll
      for (int jf = 0; jf < 2; ++jf)
        wsh[rb + r][j0 + jf * 16 + col] = bf16_rne(sc[jf][r] * inv);
    }
  }
  __syncthreads();

  // ======== phase A: P1/P2 for d0 = w*64, K=256, A (Wsm) from LDS ========
  {
    int d0 = w * 64;
    f32x4 a1[4] = {}, a2[4] = {};
    const ushort16* b1 = PvT + ((size_t)(b * DM) + d0) * TSTR;
    const ushort16* b2 = Pv2T + ((size_t)(b * DM) + d0) * TSTR;
#pragma unroll 2
    for (int kb = 0; kb < 8; ++kb) {
      bf16x8 af = *(const bf16x8*)&wsh[col][kb * 32 + ((lane >> 4) << 3)];
#pragma unroll
      for (int df = 0; df < 4; ++df) {
        bf16x8 f1 = ldfrag(b1 + (size_t)df * 16 * TSTR + kb * 32, TSTR);
        a1[df] = __builtin_amdgcn_mfma_f32_16x16x32_bf16(af, f1, a1[df], 0, 0, 0);
        bf16x8 f2 = ldfrag(b2 + (size_t)df * 16 * TSTR + kb * 32, TSTR);
        a2[df] = __builtin_amdgcn_mfma_f32_16x16x32_bf16(af, f2, a2[df], 0, 0, 0);
      }
    }
#pragma unroll
    for (int df = 0; df < 4; ++df) {
#pragma unroll
      for (int r = 0; r < 4; ++r) {
        int ig = ib + rb + r;
        int dg = d0 + df * 16 + col;
        float sv = Sv[((size_t)(b * NTOK) + ig) * DM + dg];
        float p1 = a1[df][r], p2 = a2[df][r];
        float g = 0.5f * (sv - p1) + 0.25f * (sv * sv - 2.f * sv * p1 + p2);
        gsh[rb + r][dg] = bf16_rne(g);
      }
    }
  }
  __syncthreads();

  // ======== phase B: split K-work across wave halves ========
  f32x4 acc2 = {};
  if (w < 4) {  // g @ Wv2_h^T, K=512, A from LDS
    const ushort16* wvb = Wv2b + (size_t)(h * HDIM + w * 16) * DM;
#pragma unroll 4
    for (int kb = 0; kb < 16; ++kb) {
      bf16x8 af = *(const bf16x8*)&gsh[col][kb * 32 + ((lane >> 4) << 3)];
      bf16x8 bf = ldfrag(wvb + kb * 32, DM);
      acc2 = __builtin_amdgcn_mfma_f32_16x16x32_bf16(af, bf, acc2, 0, 0, 0);
    }
  } else {      // Wsm @ V, K=256, A from LDS
    const ushort16* vtb = VTb + (size_t)(bh * HDIM + (w - 4) * 16) * TSTR;
#pragma unroll 2
    for (int kb = 0; kb < 8; ++kb) {
      bf16x8 af = *(const bf16x8*)&wsh[col][kb * 32 + ((lane >> 4) << 3)];
      bf16x8 bf = ldfrag(vtb + kb * 32, TSTR);
      acc2 = __builtin_amdgcn_mfma_f32_16x16x32_bf16(af, bf, acc2, 0, 0, 0);
    }
  }
  if (w < 4) {
#pragma unroll
    for (int r = 0; r < 4; ++r) fB[rb + r][w * 16 + col] = acc2[r];
  }
  __syncthreads();
  if (w >= 4) {
    int o = h * HDIM + (w - 4) * 16 + col;
    float bv = bv2[o];
#pragma unroll
    for (int r = 0; r < 4; ++r) {
      int ig = ib + rb + r;
      out[((size_t)(b * NTOK) + ig) * DM + o] = fB[rb + r][(w - 4) * 16 + col] + acc2[r] + bv;
    }
  }
}

extern "C" void kernel_launch(void* const* d_in, const int* in_sizes, int n_in,
                              void* d_out, int out_size, void* d_ws, size_t ws_size,
                              hipStream_t stream) {
  const float* x      = (const float*)d_in[0];
  const float* coords = (const float*)d_in[1];
  const float* Wqkv   = (const float*)d_in[2];
  const float* bqkv   = (const float*)d_in[3];
  const float* Wb1    = (const float*)d_in[4];
  const float* bb1    = (const float*)d_in[5];
  const float* Wb2    = (const float*)d_in[6];
  // d_in[7] = bb2: softmax-invariant, unused
  const float* Wv1    = (const float*)d_in[8];
  const float* bv1    = (const float*)d_in[9];
  const float* Wv2    = (const float*)d_in[10];
  const float* bv2    = (const float*)d_in[11];
  float* outp = (float*)d_out;
  float* ws = (float*)d_ws;

  const size_t SZ = (size_t)BATCH * NTOK * DM;           // 262144
  float* Svw = ws;
  float* DjT = ws + SZ;                                  // [bh][j], 4096 floats
  ushort16* SbW  = (ushort16*)(DjT + 4096);              // [bh][tok][PD]
  ushort16* Pbw  = SbW + (size_t)BATCH * NH * NTOK * PD;
  ushort16* PvT  = Pbw + (size_t)BATCH * NTOK * PD;      // [b][d][TSTR]
  ushort16* Pv2T = PvT + (size_t)BATCH * DM * TSTR;
  ushort16* Qb   = Pv2T + (size_t)BATCH * DM * TSTR;     // [bh][i][64]
  ushort16* Kb   = Qb + (size_t)BATCH * NH * NTOK * HDIM;
  ushort16* VTb  = Kb + (size_t)BATCH * NH * NTOK * HDIM;    // [bh][dp][TSTR]
  ushort16* xb   = VTb + (size_t)BATCH * NH * HDIM * TSTR;   // [row][DM]
  ushort16* Wqb  = xb + (size_t)BATCH * NTOK * DM;           // [n][DM]
  ushort16* Wv2b = Wqb + (size_t)3 * DM * DM;                // [o][DM]

  hipLaunchKernelGGL(stage0, dim3(768), dim3(256), 0, stream,
                     coords, Wb1, bb1, Wv1, bv1, Wb2, x, Wqkv, Wv2,
                     Svw, SbW, Pbw, PvT, Pv2T, DjT, xb, Wqb, Wv2b);
  hipLaunchKernelGGL(qkv_mfma, dim3(12, 32), dim3(128), 0, stream,
                     xb, Wqb, bqkv, Qb, Kb, VTb);
  hipLaunchKernelGGL(attn_fused2, dim3(16, BATCH * NH), dim3(512), 0, stream,
                     Qb, Kb, SbW, Pbw, DjT, PvT, Pv2T, Svw, Wv2b, VTb, bv2, outp);
}